// Round 11
// baseline (90.493 us; speedup 1.0000x reference)
//
#include <hip/hip_runtime.h>

#define T_LEN 512
#define LOG2E 1.4426950408889634f

typedef float f32x2 __attribute__((ext_vector_type(2)));

// v10 = R7 skeleton (2 batches/wave: lanes 0-31 batch A, 32-63 batch B;
// hl=lane&31, k=hl>>1, p=hl&1; sub-row0 = gate{i,f}[k] both sigmoid,
// sub-row1 = gate{g,o}[k]) with the h broadcast done by ds_swizzle_b32
// instead of a ds_write/ds_read round trip:
//   swizzle k (BitMode and=0,or=2k): every lane reads lane 2k of its own
//   32-group -> h_k^A to half A, h_k^B to half B, one instruction, no store.
// 16 swizzles fill v32..v47 (pairs for pk_fma). x prefetched at step head;
// in-order lgkm queue = [swz0..swz15, x_next] -> staggered waits 15,13,..,1.
// LDS per batch: [h 16][hbwd 16][x 512][pad 16] = 560 floats (x staged once;
// h region written ONCE after the loop for the epilogue).
__global__ __launch_bounds__(256, 1) void bilstm_head_kernel(
    const float* __restrict__ x,
    const float* __restrict__ W_ih_f, const float* __restrict__ W_hh_f,
    const float* __restrict__ b_ih_f, const float* __restrict__ b_hh_f,
    const float* __restrict__ W_ih_r, const float* __restrict__ W_hh_r,
    const float* __restrict__ b_ih_r, const float* __restrict__ b_hh_r,
    const float* __restrict__ W1, const float* __restrict__ b1,
    const float* __restrict__ W2, const float* __restrict__ b2,
    float* __restrict__ out)
{
    extern __shared__ float smem[];          // 8 regions * 560 floats

    const int tid  = threadIdx.x;
    const int wid  = tid >> 6;
    const int lane = tid & 63;
    const int half = lane >> 5;
    const int hl   = lane & 31;
    const int b    = blockIdx.x * 8 + wid * 2 + half;

    const int k = hl >> 1;
    const int p = hl & 1;
    const int row0 = p * 16 + k;             // sigmoid row (i or f)
    const int row1 = (2 + p) * 16 + k;       // g (tanh) or o (sigmoid)

    const float c1_0 = -LOG2E;
    const float c1_1 = (p == 0) ? (-2.0f * LOG2E) : (-LOG2E);
    const float cm1  = (p == 0) ? 2.0f : 1.0f;
    const float ca1  = (p == 0) ? -1.0f : 0.0f;
    const float k2   = -2.0f * LOG2E;

    // prescaled weights: matvec result feeds v_exp directly
    const float wih0  = W_ih_f[row0] * c1_0;
    const float bias0 = (b_ih_f[row0] + b_hh_f[row0]) * c1_0;
    const float wih1  = W_ih_f[row1] * c1_1;
    const float bias1 = (b_ih_f[row1] + b_hh_f[row1]) * c1_1;
    f32x2 w0p[8], w1p[8];
#pragma unroll
    for (int n = 0; n < 8; ++n) {
        w0p[n].x = W_hh_f[row0 * 16 + 2 * n]     * c1_0;
        w0p[n].y = W_hh_f[row0 * 16 + 2 * n + 1] * c1_0;
        w1p[n].x = W_hh_f[row1 * 16 + 2 * n]     * c1_1;
        w1p[n].y = W_hh_f[row1 * 16 + 2 * n + 1] * c1_1;
    }

    const int rbase = (wid * 2 + half) * 560;        // region base (floats)
    // stage this batch's x row (32 lanes per batch)
#pragma unroll
    for (int i = 0; i < 16; ++i)
        smem[rbase + 32 + i * 32 + hl] = x[b * T_LEN + i * 32 + hl];

    const unsigned vB = (unsigned)(rbase * 4);
    const unsigned vW = (unsigned)((rbase + p * 16 + k) * 4);
    unsigned vX = (unsigned)(rbase * 4 + 96);        // x byte base-32 (pre-bump)
    float c = 0.0f;

// One LSTM step. Head: prefetch next x, then matvec with staggered waits on
// the in-order swizzle queue. Tail: 16 ds_swizzle broadcasts of the new h.
#define LSTM_STEP(XC, XN, XOFF) \
    "ds_read_b32 " XN ", %[vX] offset:" XOFF "\n\t" \
    "s_waitcnt lgkmcnt(15)\n\t" \
    "v_fma_f32 v20, " XC ", %[wih0], %[bias0]\n\t" \
    "v_mov_b32 v21, 0\n\t" \
    "v_fma_f32 v22, " XC ", %[wih1], %[bias1]\n\t" \
    "v_mov_b32 v23, 0\n\t" \
    "v_pk_fma_f32 v[20:21], v[32:33], %[w00], v[20:21]\n\t" \
    "v_pk_fma_f32 v[22:23], v[32:33], %[w10], v[22:23]\n\t" \
    "s_waitcnt lgkmcnt(13)\n\t" \
    "v_pk_fma_f32 v[20:21], v[34:35], %[w01], v[20:21]\n\t" \
    "v_pk_fma_f32 v[22:23], v[34:35], %[w11], v[22:23]\n\t" \
    "s_waitcnt lgkmcnt(11)\n\t" \
    "v_pk_fma_f32 v[20:21], v[36:37], %[w02], v[20:21]\n\t" \
    "v_pk_fma_f32 v[22:23], v[36:37], %[w12], v[22:23]\n\t" \
    "s_waitcnt lgkmcnt(9)\n\t" \
    "v_pk_fma_f32 v[20:21], v[38:39], %[w03], v[20:21]\n\t" \
    "v_pk_fma_f32 v[22:23], v[38:39], %[w13], v[22:23]\n\t" \
    "s_waitcnt lgkmcnt(7)\n\t" \
    "v_pk_fma_f32 v[20:21], v[40:41], %[w04], v[20:21]\n\t" \
    "v_pk_fma_f32 v[22:23], v[40:41], %[w14], v[22:23]\n\t" \
    "s_waitcnt lgkmcnt(5)\n\t" \
    "v_pk_fma_f32 v[20:21], v[42:43], %[w05], v[20:21]\n\t" \
    "v_pk_fma_f32 v[22:23], v[42:43], %[w15], v[22:23]\n\t" \
    "s_waitcnt lgkmcnt(3)\n\t" \
    "v_pk_fma_f32 v[20:21], v[44:45], %[w06], v[20:21]\n\t" \
    "v_pk_fma_f32 v[22:23], v[44:45], %[w16], v[22:23]\n\t" \
    "s_waitcnt lgkmcnt(1)\n\t" \
    "v_pk_fma_f32 v[20:21], v[46:47], %[w07], v[20:21]\n\t" \
    "v_pk_fma_f32 v[22:23], v[46:47], %[w17], v[22:23]\n\t" \
    "v_add_f32 v20, v20, v21\n\t" \
    "v_add_f32 v22, v22, v23\n\t" \
    "v_exp_f32 v24, v20\n\t" \
    "v_exp_f32 v25, v22\n\t" \
    "s_nop 0\n\t" \
    "v_add_f32 v24, 1.0, v24\n\t" \
    "v_add_f32 v25, 1.0, v25\n\t" \
    "v_rcp_f32 v24, v24\n\t" \
    "v_rcp_f32 v25, v25\n\t" \
    "s_nop 1\n\t" \
    "v_fma_f32 v25, v25, %[cm1], %[ca1]\n\t" \
    "s_nop 1\n\t" \
    "v_mov_b32_dpp v26, v24 quad_perm:[1,0,3,2] row_mask:0xf bank_mask:0xf\n\t" \
    "v_mov_b32_dpp v27, v25 quad_perm:[1,0,3,2] row_mask:0xf bank_mask:0xf\n\t" \
    "v_mul_f32 v28, v24, v25\n\t" \
    "v_fma_f32 %[c], v26, %[c], v28\n\t" \
    "v_mul_f32 v28, %[k2], %[c]\n\t" \
    "v_exp_f32 v28, v28\n\t" \
    "s_nop 1\n\t" \
    "v_add_f32 v28, 1.0, v28\n\t" \
    "v_rcp_f32 v28, v28\n\t" \
    "s_nop 1\n\t" \
    "v_fma_f32 v28, v28, 2.0, -1.0\n\t" \
    "v_mul_f32 v29, v27, v28\n\t" \
    "ds_swizzle_b32 v32, v29 offset:0x000\n\t" \
    "ds_swizzle_b32 v33, v29 offset:0x040\n\t" \
    "ds_swizzle_b32 v34, v29 offset:0x080\n\t" \
    "ds_swizzle_b32 v35, v29 offset:0x0C0\n\t" \
    "ds_swizzle_b32 v36, v29 offset:0x100\n\t" \
    "ds_swizzle_b32 v37, v29 offset:0x140\n\t" \
    "ds_swizzle_b32 v38, v29 offset:0x180\n\t" \
    "ds_swizzle_b32 v39, v29 offset:0x1C0\n\t" \
    "ds_swizzle_b32 v40, v29 offset:0x200\n\t" \
    "ds_swizzle_b32 v41, v29 offset:0x240\n\t" \
    "ds_swizzle_b32 v42, v29 offset:0x280\n\t" \
    "ds_swizzle_b32 v43, v29 offset:0x2C0\n\t" \
    "ds_swizzle_b32 v44, v29 offset:0x300\n\t" \
    "ds_swizzle_b32 v45, v29 offset:0x340\n\t" \
    "ds_swizzle_b32 v46, v29 offset:0x380\n\t" \
    "ds_swizzle_b32 v47, v29 offset:0x3C0\n\t"

    asm volatile(
        // preamble: x0 read + 16 swizzles of zeroed v29 -> same queue shape
        "v_mov_b32 v29, 0\n\t"
        "ds_read_b32 v30, %[vB] offset:128\n\t"
        "ds_swizzle_b32 v32, v29 offset:0x000\n\t"
        "ds_swizzle_b32 v33, v29 offset:0x040\n\t"
        "ds_swizzle_b32 v34, v29 offset:0x080\n\t"
        "ds_swizzle_b32 v35, v29 offset:0x0C0\n\t"
        "ds_swizzle_b32 v36, v29 offset:0x100\n\t"
        "ds_swizzle_b32 v37, v29 offset:0x140\n\t"
        "ds_swizzle_b32 v38, v29 offset:0x180\n\t"
        "ds_swizzle_b32 v39, v29 offset:0x1C0\n\t"
        "ds_swizzle_b32 v40, v29 offset:0x200\n\t"
        "ds_swizzle_b32 v41, v29 offset:0x240\n\t"
        "ds_swizzle_b32 v42, v29 offset:0x280\n\t"
        "ds_swizzle_b32 v43, v29 offset:0x2C0\n\t"
        "ds_swizzle_b32 v44, v29 offset:0x300\n\t"
        "ds_swizzle_b32 v45, v29 offset:0x340\n\t"
        "ds_swizzle_b32 v46, v29 offset:0x380\n\t"
        "ds_swizzle_b32 v47, v29 offset:0x3C0\n\t"
        "s_mov_b32 s20, 0\n\t"
        "1:\n\t"
        "v_add_u32 %[vX], 32, %[vX]\n\t"
        LSTM_STEP("v30", "v31", "4")
        LSTM_STEP("v31", "v30", "8")
        LSTM_STEP("v30", "v31", "12")
        LSTM_STEP("v31", "v30", "16")
        LSTM_STEP("v30", "v31", "20")
        LSTM_STEP("v31", "v30", "24")
        LSTM_STEP("v30", "v31", "28")
        LSTM_STEP("v31", "v30", "32")
        "s_add_u32 s20, s20, 1\n\t"
        "s_cmp_lt_u32 s20, 64\n\t"
        "s_cbranch_scc1 1b\n\t"
        // publish final h for the epilogue: p0 lanes write h[k] to rbase+k,
        // p1 lanes write junk to rbase+16+k (overwritten by reverse step)
        "ds_write_b32 %[vW], v29\n\t"
        "s_waitcnt lgkmcnt(0)\n\t"
        : [c]"+v"(c), [vX]"+v"(vX)
        : [vB]"v"(vB), [vW]"v"(vW),
          [wih0]"v"(wih0), [bias0]"v"(bias0),
          [wih1]"v"(wih1), [bias1]"v"(bias1),
          [cm1]"v"(cm1), [ca1]"v"(ca1), [k2]"v"(k2),
          [w00]"v"(w0p[0]), [w01]"v"(w0p[1]), [w02]"v"(w0p[2]), [w03]"v"(w0p[3]),
          [w04]"v"(w0p[4]), [w05]"v"(w0p[5]), [w06]"v"(w0p[6]), [w07]"v"(w0p[7]),
          [w10]"v"(w1p[0]), [w11]"v"(w1p[1]), [w12]"v"(w1p[2]), [w13]"v"(w1p[3]),
          [w14]"v"(w1p[4]), [w15]"v"(w1p[5]), [w16]"v"(w1p[6]), [w17]"v"(w1p[7])
        : "v20","v21","v22","v23","v24","v25","v26","v27","v28","v29",
          "v30","v31","v32","v33","v34","v35","v36","v37","v38","v39",
          "v40","v41","v42","v43","v44","v45","v46","v47",
          "s20","scc","memory");
#undef LSTM_STEP

    // ---- reverse direction: one step on x[:, T-1], zero state; lanes hl<16
    if (hl < 16) {
        const int j = hl;
        const float xl = smem[rbase + 32 + 511];
        const float zi = fmaf(xl, W_ih_r[j],      b_ih_r[j]      + b_hh_r[j]);
        const float zg = fmaf(xl, W_ih_r[32 + j], b_ih_r[32 + j] + b_hh_r[32 + j]);
        const float zo = fmaf(xl, W_ih_r[48 + j], b_ih_r[48 + j] + b_hh_r[48 + j]);
        const float si = __builtin_amdgcn_rcpf(1.0f + __builtin_amdgcn_exp2f(-zi * LOG2E));
        const float tg = fmaf(__builtin_amdgcn_rcpf(1.0f + __builtin_amdgcn_exp2f(-2.0f * zg * LOG2E)), 2.0f, -1.0f);
        const float so = __builtin_amdgcn_rcpf(1.0f + __builtin_amdgcn_exp2f(-zo * LOG2E));
        const float cr = si * tg;
        const float th = fmaf(__builtin_amdgcn_rcpf(1.0f + __builtin_amdgcn_exp2f(-2.0f * cr * LOG2E)), 2.0f, -1.0f);
        smem[rbase + 16 + j] = so * th;
    }
    __syncthreads();

    // ---- MLP head ----
    const int m = hl & 15;
    float hid = b1[m];
#pragma unroll
    for (int n = 0; n < 16; ++n) hid = fmaf(smem[rbase + n],      W1[m * 32 + n],      hid);
#pragma unroll
    for (int n = 0; n < 16; ++n) hid = fmaf(smem[rbase + 16 + n], W1[m * 32 + 16 + n], hid);
    hid = (hid > 0.0f) ? hid : (0.2f * hid);

    float v = hid * W2[m];
    v += __shfl_xor(v, 1);
    v += __shfl_xor(v, 2);
    v += __shfl_xor(v, 4);
    v += __shfl_xor(v, 8);
    if (hl == 0) out[b] = v + b2[0];
}

extern "C" void kernel_launch(void* const* d_in, const int* in_sizes, int n_in,
                              void* d_out, int out_size, void* d_ws, size_t ws_size,
                              hipStream_t stream) {
    const float* x      = (const float*)d_in[0];
    const float* W_ih_f = (const float*)d_in[1];
    const float* W_hh_f = (const float*)d_in[2];
    const float* b_ih_f = (const float*)d_in[3];
    const float* b_hh_f = (const float*)d_in[4];
    const float* W_ih_r = (const float*)d_in[5];
    const float* W_hh_r = (const float*)d_in[6];
    const float* b_ih_r = (const float*)d_in[7];
    const float* b_hh_r = (const float*)d_in[8];
    const float* W1     = (const float*)d_in[9];
    const float* b1     = (const float*)d_in[10];
    const float* W2     = (const float*)d_in[11];
    const float* b2     = (const float*)d_in[12];
    float* out = (float*)d_out;

    const int B = in_sizes[0] / T_LEN;   // 2048
    dim3 grid(B / 8), block(256);
    size_t lds_bytes = 8 * 560 * sizeof(float);   // 17920 B/block
    hipLaunchKernelGGL(bilstm_head_kernel, grid, block, lds_bytes, stream,
                       x, W_ih_f, W_hh_f, b_ih_f, b_hh_f,
                       W_ih_r, W_hh_r, b_ih_r, b_hh_r,
                       W1, b1, W2, b2, out);
}